// Round 5
// baseline (76.097 us; speedup 1.0000x reference)
//
#include <hip/hip_runtime.h>

typedef unsigned short u16;
typedef __bf16 bf16x8 __attribute__((ext_vector_type(8)));
typedef float f32x16 __attribute__((ext_vector_type(16)));

union B8 { bf16x8 v; u16 s[8]; unsigned u[4]; uint4 u4; };

__device__ __forceinline__ unsigned cvtpk(float a, float b) {
    unsigned r;
    asm("v_cvt_pk_bf16_f32 %0, %1, %2" : "=v"(r) : "v"(a), "v"(b));
    return r;
}
__device__ __forceinline__ float ex2(float x) { return __builtin_amdgcn_exp2f(x); }
__device__ __forceinline__ void swap32(unsigned &a, unsigned &b) {
    asm("v_permlane32_swap_b32 %0, %1" : "+v"(a), "+v"(b));
}
__device__ __forceinline__ B8 load_w8(const float* __restrict__ p, float s) {
    float4 lo = ((const float4*)p)[0];
    float4 hi = ((const float4*)p)[1];
    B8 r;
    r.u[0] = cvtpk(lo.x * s, lo.y * s);
    r.u[1] = cvtpk(lo.z * s, lo.w * s);
    r.u[2] = cvtpk(hi.x * s, hi.y * s);
    r.u[3] = cvtpk(hi.z * s, hi.w * s);
    return r;
}
__device__ __forceinline__ f32x16 mfma32(const B8 a, const B8 b, f32x16 c) {
    return __builtin_amdgcn_mfma_f32_32x32x16_bf16(a.v, b.v, c, 0, 0, 0);
}
// K LDS: [512 tok][32 ck] u16, 4x16B slots per row XOR-swizzled by (tok>>1)&3
__device__ __forceinline__ int kidx(int row, int sl) {
    return row * 32 + (((sl ^ (row >> 1)) & 3) << 3);
}
// D-regs (rows (r&3)+8*(r>>2)+4*h5) -> two B-fragments (k-chunks of 16) via cvtpk+permlane
__device__ __forceinline__ void build_b(const float* p, B8& b0, B8& b1) {
    unsigned c0 = cvtpk(p[0], p[1]),   c1 = cvtpk(p[2], p[3]);
    unsigned c2 = cvtpk(p[4], p[5]),   c3 = cvtpk(p[6], p[7]);
    unsigned c4 = cvtpk(p[8], p[9]),   c5 = cvtpk(p[10], p[11]);
    unsigned c6 = cvtpk(p[12], p[13]), c7 = cvtpk(p[14], p[15]);
    swap32(c0, c2); swap32(c1, c3); swap32(c4, c6); swap32(c5, c7);
    b0.u[0] = c0; b0.u[1] = c1; b0.u[2] = c2; b0.u[3] = c3;
    b1.u[0] = c4; b1.u[1] = c5; b1.u[2] = c6; b1.u[3] = c7;
}

// LDS (u16 idx): K [512][32] @0 (32768B) | V [64][520] @16384 (66560B) | X [256][64] swz @49664 (32768B)
// epilogue: 4 wave-slots of 32KB f32 fout overlay @byte 0 (after barrier 5)
#define VOFF 16384
#define XOFF 49664
#define NSM  66048

__global__ __launch_bounds__(256, 1)
void psab_fused(const float* __restrict__ x,
                const float* __restrict__ wk, const float* __restrict__ bk,
                const float* __restrict__ wv, const float* __restrict__ bv,
                const float* __restrict__ wo, const float* __restrict__ bo,
                float* __restrict__ out)
{
    __shared__ __align__(16) u16 smem[NSM];
    const int t    = threadIdx.x;
    const int lane = t & 63;
    const int wid  = t >> 6;        // 4 waves
    const int cl   = lane & 31;
    const int h5   = lane >> 5;

    const int bid = blockIdx.x;
    const int n   = (bid & 7) * 64 + (bid >> 3);   // XCD-bijective swizzle
    const int sh = n >> 6, sw = (n >> 3) & 7, sd = n & 7;
    const size_t base_vox = (size_t)(sh * 8) * 4096 + (size_t)(sw * 8) * 64 + (size_t)(sd * 8);

    const float WSC = 0.50506330f;   // sqrt(log2(e)/sqrt(32)) folded into K weights

    // every wave loads all projection weights (rows = out-channel = cl)
    B8 wkB[4], wvB[2][4];
#pragma unroll
    for (int kc = 0; kc < 4; ++kc)
        wkB[kc] = load_w8(wk + cl * 64 + kc * 16 + h5 * 8, WSC);
#pragma unroll
    for (int nb = 0; nb < 2; ++nb)
#pragma unroll
        for (int kc = 0; kc < 4; ++kc)
            wvB[nb][kc] = load_w8(wv + (nb * 32 + cl) * 64 + kc * 16 + h5 * 8, 1.0f);
    float bkv[16];
#pragma unroll
    for (int r = 0; r < 16; ++r)
        bkv[r] = bk[(r & 3) + 8 * (r >> 2) + 4 * h5] * WSC;
    const float vb0 = bv[cl], vb1 = bv[32 + cl];

    const f32x16 z16 = {0,0,0,0,0,0,0,0,0,0,0,0,0,0,0,0};

    // ---- X staging: 2 chunks x 256 tok; thread: c = lane, rows rr = wid + 4i ----
    const int cS = t & 63;
    float4 L4[8], H4[8];
#define LDX(cc)                                                                               \
    _Pragma("unroll")                                                                         \
    for (int i = 0; i < 8; ++i) {                                                             \
        const int rr = wid + i * 4;                                                           \
        const float* gp = x + (size_t)cS * 262144 + base_vox                                  \
                        + ((cc) * 4 + (rr >> 3)) * 4096 + (rr & 7) * 64;                      \
        L4[i] = ((const float4*)gp)[0];                                                       \
        H4[i] = ((const float4*)gp)[1];                                                       \
    }
    // X[ltok][c] u16, row = 64 u16 = 8 slots of 8; phys slot = (c>>3) ^ (ltok&7)
#define STX()                                                                                 \
    _Pragma("unroll")                                                                         \
    for (int i = 0; i < 8; ++i) {                                                             \
        const int rr = wid + i * 4;                                                           \
        unsigned a0 = cvtpk(L4[i].x, L4[i].y), a1 = cvtpk(L4[i].z, L4[i].w);                  \
        unsigned a2 = cvtpk(H4[i].x, H4[i].y), a3 = cvtpk(H4[i].z, H4[i].w);                  \
        const u16 vals[8] = { (u16)a0, (u16)(a0 >> 16), (u16)a1, (u16)(a1 >> 16),             \
                              (u16)a2, (u16)(a2 >> 16), (u16)a3, (u16)(a3 >> 16) };           \
        _Pragma("unroll")                                                                     \
        for (int j = 0; j < 8; ++j)                                                           \
            smem[XOFF + (rr * 8 + j) * 64 + (((cS >> 3) ^ j) << 3) + (cS & 7)] = vals[j];     \
    }

    LDX(0)
    STX()
    __syncthreads();                          // (1) X0 visible
    LDX(1)                                    // prefetch chunk1 under proj-chunk0 compute

#pragma unroll
    for (int cc = 0; cc < 2; ++cc) {
#pragma unroll
        for (int sb = 0; sb < 2; ++sb) {
            const int ltok = wid * 64 + sb * 32 + cl;   // local token (A/B row)
            const int tokb = cc * 256 + wid * 64 + sb * 32;
            B8 ax[4];
#pragma unroll
            for (int kc = 0; kc < 4; ++kc) {
                const int slot = (kc * 2 + h5) ^ (ltok & 7);
                ax[kc].u4 = *(const uint4*)&smem[XOFF + ltok * 64 + (slot << 3)];
            }
            // K proj, swapped operands: D col = tok = cl, rows = ck -> packed uint2 stores
            f32x16 kd = mfma32(wkB[0], ax[0], z16);
            kd = mfma32(wkB[1], ax[1], kd);
            kd = mfma32(wkB[2], ax[2], kd);
            kd = mfma32(wkB[3], ax[3], kd);
            const int trow = tokb + cl;
#pragma unroll
            for (int g = 0; g < 4; ++g) {
                uint2 pk;
                pk.x = cvtpk(kd[4 * g + 0] + bkv[4 * g + 0], kd[4 * g + 1] + bkv[4 * g + 1]);
                pk.y = cvtpk(kd[4 * g + 2] + bkv[4 * g + 2], kd[4 * g + 3] + bkv[4 * g + 3]);
                *(uint2*)&smem[kidx(trow, g) + 4 * h5] = pk;
            }
            // V proj: D col = cv = cl, rows = tok -> V^T[cv][tok] packed uint2
#pragma unroll
            for (int nb = 0; nb < 2; ++nb) {
                f32x16 vd = mfma32(ax[0], wvB[nb][0], z16);
                vd = mfma32(ax[1], wvB[nb][1], vd);
                vd = mfma32(ax[2], wvB[nb][2], vd);
                vd = mfma32(ax[3], wvB[nb][3], vd);
                const int cv = nb * 32 + cl;
                const float vb = nb ? vb1 : vb0;
#pragma unroll
                for (int rq = 0; rq < 4; ++rq) {
                    uint2 pk;
                    pk.x = cvtpk(vd[rq * 4 + 0] + vb, vd[rq * 4 + 1] + vb);
                    pk.y = cvtpk(vd[rq * 4 + 2] + vb, vd[rq * 4 + 3] + vb);
                    *(uint2*)&smem[VOFF + cv * 520 + tokb + rq * 8 + 4 * h5] = pk;
                }
            }
        }
        if (cc == 0) {
            __syncthreads();                  // (2) X0 readers done
            STX()
            __syncthreads();                  // (3) X1 visible
        }
    }
    __syncthreads();                          // (4) K/V complete

    // ---- attention: wave owns q = wid*128 + qb*32 + cl (4 q-blocks = 4 independent chains) ----
    B8 qB[4][2];
#pragma unroll
    for (int qb = 0; qb < 4; ++qb)
#pragma unroll
        for (int kc = 0; kc < 2; ++kc)
            qB[qb][kc].u4 = *(const uint4*)&smem[kidx(wid * 128 + qb * 32 + cl, 2 * kc + h5)];

    f32x16 ctx00 = z16, ctx01 = z16, ctx10 = z16, ctx11 = z16;
    f32x16 ctx20 = z16, ctx21 = z16, ctx30 = z16, ctx31 = z16;
    float ls0 = 0.f, ls1 = 0.f, ls2 = 0.f, ls3 = 0.f;

#define SM(qb, sv, c0, c1)                                                                    \
    {                                                                                         \
        float p[16];                                                                          \
        _Pragma("unroll")                                                                     \
        for (int i = 0; i < 16; ++i) p[i] = ex2(sv[i]);                                       \
        ls##qb += (((p[0]+p[1])+(p[2]+p[3]))+((p[4]+p[5])+(p[6]+p[7])))                       \
                + (((p[8]+p[9])+(p[10]+p[11]))+((p[12]+p[13])+(p[14]+p[15])));                \
        B8 pb0, pb1;                                                                          \
        build_b(p, pb0, pb1);                                                                 \
        c0 = mfma32(va00, pb0, c0);                                                           \
        c0 = mfma32(va01, pb1, c0);                                                           \
        c1 = mfma32(va10, pb0, c1);                                                           \
        c1 = mfma32(va11, pb1, c1);                                                           \
    }

#pragma unroll 2
    for (int ci = 0; ci < 16; ++ci) {
        const int m0 = ci * 32;
        B8 kA0, kA1, va00, va01, va10, va11;
        kA0.u4  = *(const uint4*)&smem[kidx(m0 + cl, h5)];
        kA1.u4  = *(const uint4*)&smem[kidx(m0 + cl, 2 + h5)];
        va00.u4 = *(const uint4*)&smem[VOFF + cl * 520 + m0 + h5 * 8];
        va01.u4 = *(const uint4*)&smem[VOFF + cl * 520 + m0 + 16 + h5 * 8];
        va10.u4 = *(const uint4*)&smem[VOFF + (32 + cl) * 520 + m0 + h5 * 8];
        va11.u4 = *(const uint4*)&smem[VOFF + (32 + cl) * 520 + m0 + 16 + h5 * 8];

        // 4 independent QK chains (S^T[m][q], log2 domain)
        f32x16 s0 = mfma32(kA0, qB[0][0], z16); s0 = mfma32(kA1, qB[0][1], s0);
        f32x16 s1 = mfma32(kA0, qB[1][0], z16); s1 = mfma32(kA1, qB[1][1], s1);
        f32x16 s2 = mfma32(kA0, qB[2][0], z16); s2 = mfma32(kA1, qB[2][1], s2);
        f32x16 s3 = mfma32(kA0, qB[3][0], z16); s3 = mfma32(kA1, qB[3][1], s3);

        SM(0, s0, ctx00, ctx01)
        SM(1, s1, ctx10, ctx11)
        SM(2, s2, ctx20, ctx21)
        SM(3, s3, ctx30, ctx31)
    }

    ls0 += __shfl_xor(ls0, 32);
    ls1 += __shfl_xor(ls1, 32);
    ls2 += __shfl_xor(ls2, 32);
    ls3 += __shfl_xor(ls3, 32);
    const float inv0 = 1.0f / ls0, inv1 = 1.0f / ls1;
    const float inv2 = 1.0f / ls2, inv3 = 1.0f / ls3;

    // out-proj A-frags + ctx -> B-frags in registers
    B8 aw[2][4];
#pragma unroll
    for (int cob = 0; cob < 2; ++cob)
#pragma unroll
        for (int kc = 0; kc < 4; ++kc)
            aw[cob][kc] = load_w8(wo + (cob * 32 + cl) * 64 + kc * 16 + h5 * 8, 1.0f);

    float pn[16];
    B8 cq0[4], cq1[4], cq2[4], cq3[4];
#pragma unroll
    for (int i = 0; i < 16; ++i) pn[i] = ctx00[i] * inv0;
    build_b(pn, cq0[0], cq0[1]);
#pragma unroll
    for (int i = 0; i < 16; ++i) pn[i] = ctx01[i] * inv0;
    build_b(pn, cq0[2], cq0[3]);
#pragma unroll
    for (int i = 0; i < 16; ++i) pn[i] = ctx10[i] * inv1;
    build_b(pn, cq1[0], cq1[1]);
#pragma unroll
    for (int i = 0; i < 16; ++i) pn[i] = ctx11[i] * inv1;
    build_b(pn, cq1[2], cq1[3]);
#pragma unroll
    for (int i = 0; i < 16; ++i) pn[i] = ctx20[i] * inv2;
    build_b(pn, cq2[0], cq2[1]);
#pragma unroll
    for (int i = 0; i < 16; ++i) pn[i] = ctx21[i] * inv2;
    build_b(pn, cq2[2], cq2[3]);
#pragma unroll
    for (int i = 0; i < 16; ++i) pn[i] = ctx30[i] * inv3;
    build_b(pn, cq3[0], cq3[1]);
#pragma unroll
    for (int i = 0; i < 16; ++i) pn[i] = ctx31[i] * inv3;
    build_b(pn, cq3[2], cq3[3]);

    __syncthreads();                          // (5) K/V readers done; LDS -> fout slots

    float* fout = (float*)((char*)smem + wid * 32768);   // [64 co][128 q] f32
#define OPROJ(qb, cq)                                                                         \
    _Pragma("unroll")                                                                         \
    for (int cob = 0; cob < 2; ++cob) {                                                       \
        f32x16 od = mfma32(aw[cob][0], cq[0], z16);                                           \
        od = mfma32(aw[cob][1], cq[1], od);                                                   \
        od = mfma32(aw[cob][2], cq[2], od);                                                   \
        od = mfma32(aw[cob][3], cq[3], od);                                                   \
        _Pragma("unroll")                                                                     \
        for (int r = 0; r < 16; ++r) {                                                        \
            const int row = cob * 32 + (r & 3) + 8 * (r >> 2) + 4 * h5;                       \
            fout[row * 128 + (qb) * 32 + cl] = od[r];                                         \
        }                                                                                     \
    }
    OPROJ(0, cq0)
    OPROJ(1, cq1)
    OPROJ(2, cq2)
    OPROJ(3, cq3)

    // global store: wave covers hb = wid*2 + (qlocal>>6); q-local = qg*4+e
    float* outw = out + base_vox + (size_t)(wid * 2) * 4096;
    const int qg  = lane & 31;
    const int co0 = lane >> 5;
    const int hbl = qg >> 4;
    const int wb  = (qg >> 1) & 7;
    const int db0 = (qg & 1) * 4;
#pragma unroll
    for (int it = 0; it < 32; ++it) {
        const int co = it * 2 + co0;
        float4 v4 = *(const float4*)&fout[co * 128 + qg * 4];
        const float bco = bo[co];
        v4.x += bco; v4.y += bco; v4.z += bco; v4.w += bco;
        *(float4*)&outw[(size_t)co * 262144 + hbl * 4096 + wb * 64 + db0] = v4;
    }
}

extern "C" void kernel_launch(void* const* d_in, const int* in_sizes, int n_in,
                              void* d_out, int out_size, void* d_ws, size_t ws_size,
                              hipStream_t stream) {
    const float* x  = (const float*)d_in[0];
    const float* wk = (const float*)d_in[1];
    const float* bk = (const float*)d_in[2];
    const float* wv = (const float*)d_in[3];
    const float* bv = (const float*)d_in[4];
    const float* wo = (const float*)d_in[5];
    const float* bo = (const float*)d_in[6];
    float* o = (float*)d_out;
    psab_fused<<<dim3(512), dim3(256), 0, stream>>>(x, wk, bk, wv, bv, wo, bo, o);
}